// Round 6
// baseline (659.670 us; speedup 1.0000x reference)
//
#include <hip/hip_runtime.h>
#include <math.h>

#define B_  8
#define L_  2500
#define D_  512
#define Y_  8921
#define LP  2560    // L padded
#define YP  8960    // Y padded to 70*128

// ws layout: fp16 X[B_][LP][D_] | U[YP][D_] | F[YP][D_]
// then fp32  denG[B_][YP] | numG[B_][YP]
#define WS_F16_HALVES  (B_ * LP * D_ + 2 * YP * D_)
#define ACC_FLOATS     (2 * B_ * YP)

typedef _Float16 f16x8 __attribute__((ext_vector_type(8)));
typedef _Float16 f16x4 __attribute__((ext_vector_type(4)));
typedef float    f32x4 __attribute__((ext_vector_type(4)));

__device__ __forceinline__ void load_lds16(const _Float16* g, _Float16* l) {
  __builtin_amdgcn_global_load_lds(
      (const __attribute__((address_space(1))) unsigned int*)g,
      (__attribute__((address_space(3))) unsigned int*)l, 16, 0, 0);
}

__global__ void k_convert(const float* __restrict__ x,
                          const float* __restrict__ Uw,
                          const float* __restrict__ Fw,
                          _Float16* __restrict__ ws,
                          float* __restrict__ loss_slot) {
  if (blockIdx.x == 0 && threadIdx.x == 0) *loss_slot = 0.0f;
  const int NX = B_ * LP * (D_ / 8);   // 1310720
  const int NU = YP * (D_ / 8);        // 573440
  int idx = blockIdx.x * 256 + threadIdx.x;
  if (idx < ACC_FLOATS) ((float*)(ws + WS_F16_HALVES))[idx] = 0.0f;
  const float* src = nullptr;
  if (idx < NX) {
    int b  = idx / (LP * 64);
    int r  = idx - b * (LP * 64);
    int l  = r >> 6;
    int d8 = r & 63;
    if (l < L_) src = x + (((long)b * L_ + l) * D_ + d8 * 8);
  } else if (idx < NX + NU) {
    int u = idx - NX;
    int y = u >> 6, d8 = u & 63;
    if (y < Y_) src = Uw + ((long)y * D_ + d8 * 8);
  } else {
    int u = idx - NX - NU;
    int y = u >> 6, d8 = u & 63;
    if (y < Y_) src = Fw + ((long)y * D_ + d8 * 8);
  }
  f16x8 o;
  if (src) {
    const float4* s4 = (const float4*)src;
    float4 a = s4[0], c = s4[1];
    o[0] = (_Float16)a.x; o[1] = (_Float16)a.y; o[2] = (_Float16)a.z; o[3] = (_Float16)a.w;
    o[4] = (_Float16)c.x; o[5] = (_Float16)c.y; o[6] = (_Float16)c.z; o[7] = (_Float16)c.w;
  } else {
    for (int i = 0; i < 8; ++i) o[i] = (_Float16)0.0f;
  }
  ((f16x8*)ws)[idx] = o;
}

// GEMM-split flash: 8 waves = (wy,wl,g); g=0 waves compute S=U@X^T, g=1 waves
// compute C=F@X^T on the SAME 64x64 coordinates. Tile 128y x 128l, BK=64.
// Per lt: S-waves exp(S)->fp16 into E (overlaid on staging LDS, XOR-swizzled
// [l][y]), accumulate den; C-waves read E, accumulate num. Global fp32
// accumulators + k_final. Pad x rows are exactly zero -> pad cols add exactly
// (1,0) to (den,num); k_final subtracts LP-L_.
__global__ __launch_bounds__(512, 4)
void k_attn(const _Float16* __restrict__ ws,
            float* __restrict__ accG) {
  __shared__ __align__(16) _Float16 TILE[24576];   // U(8K) | F(8K) | X(8K) halves
  _Float16* UT = TILE;
  _Float16* FT = TILE + 8192;
  _Float16* XT = TILE + 16384;
  _Float16* E  = TILE;            // 128*128 fp16 overlay (32 KB) on UT+FT

  const int tid  = threadIdx.x;
  const int lane = tid & 63;
  const int wave = tid >> 6;           // 0..7
  const int g  = wave & 1;             // 0 = S (U), 1 = C (F)
  const int wy = (wave >> 1) & 1;
  const int wl = wave >> 2;            // 0..1
  const int yt = blockIdx.x;
  const int b  = blockIdx.y;
  const int lh = blockIdx.z;

  const _Float16* Xg = ws + (long)b * LP * D_ + (long)lh * (LP / 2) * D_;
  const _Float16* Ug = ws + (long)B_ * LP * D_ + (long)yt * 128 * D_;
  const _Float16* Fg = Ug + (long)YP * D_;

  // staging: 48 segments of 1KB (8 rows x 64 halves); 6 per wave
  const int srow = lane >> 3;
  const int sg8  = ((lane & 7) ^ srow) * 8;
  const _Float16* gsrc[6];
  _Float16*       gdst[6];
  #pragma unroll
  for (int i = 0; i < 6; ++i) {
    int seg = wave * 6 + i;
    const _Float16* base;
    int r;
    if (seg < 16)      { base = Ug; r = seg * 8; }
    else if (seg < 32) { base = Fg; r = (seg - 16) * 8; }
    else               { base = Xg; r = (seg - 32) * 8; }   // + lt*128 rows later
    gsrc[i] = base + (long)(r + srow) * D_ + sg8;
    gdst[i] = TILE + seg * 512;
  }

  // compute geometry
  const int arow = wy * 64 + (lane & 15);
  const int xrow = wl * 64 + (lane & 15);
  const int r7   = lane & 7;
  const int gb   = lane >> 4;
  const int c    = lane & 15;
  const _Float16* AT = g ? FT : UT;

  float redP[4][4];     // den partials (S-waves) or num partials (C-waves)
  for (int i = 0; i < 4; ++i)
    for (int v = 0; v < 4; ++v) redP[i][v] = 0.0f;

  for (int lt = 0; lt < 10; ++lt) {
    f32x4 acc[4][4];
    #pragma unroll
    for (int mi = 0; mi < 4; ++mi)
      for (int ni = 0; ni < 4; ++ni) {
        f32x4 z = {0.0f, 0.0f, 0.0f, 0.0f};
        acc[mi][ni] = z;
      }
    const long xofs = (long)lt * 128 * D_;
    for (int kk = 0; kk < D_; kk += 64) {
      __syncthreads();
      #pragma unroll
      for (int i = 0; i < 6; ++i) {
        const _Float16* s = gsrc[i] + kk;
        if (wave * 6 + i >= 32) s += xofs;
        load_lds16(s, gdst[i]);
      }
      __syncthreads();
      #pragma unroll
      for (int ks = 0; ks < 2; ++ks) {
        int off = (((ks * 4 + gb) ^ r7) * 8);
        f16x8 bx[4];
        #pragma unroll
        for (int ni = 0; ni < 4; ++ni)
          bx[ni] = *(const f16x8*)&XT[(xrow + ni * 16) * 64 + off];
        #pragma unroll
        for (int mi = 0; mi < 4; ++mi) {
          f16x8 a = *(const f16x8*)&AT[(arow + mi * 16) * 64 + off];
          #pragma unroll
          for (int ni = 0; ni < 4; ++ni)
            acc[mi][ni] = __builtin_amdgcn_mfma_f32_16x16x32_f16(a, bx[ni], acc[mi][ni], 0, 0, 0);
        }
      }
    }
    // ---- P exchange: S-waves exp -> E (fp16, swizzled [l][y]), C-waves read
    __syncthreads();                       // tile reads done; safe to overlay E
    if (g == 0) {
      #pragma unroll
      for (int mi = 0; mi < 4; ++mi) {
        int yg = wy * 16 + mi * 4 + gb;    // y>>2
        #pragma unroll
        for (int ni = 0; ni < 4; ++ni) {
          f16x4 ev;
          #pragma unroll
          for (int v = 0; v < 4; ++v) {
            float e = __expf(acc[mi][ni][v]);
            redP[mi][v] += e;
            ev[v] = (_Float16)e;
          }
          int l = wl * 64 + ni * 16 + c;
          *(f16x4*)&E[l * 128 + ((yg ^ c) << 2)] = ev;
        }
      }
    }
    __syncthreads();
    if (g == 1) {
      #pragma unroll
      for (int mi = 0; mi < 4; ++mi) {
        int yg = wy * 16 + mi * 4 + gb;
        #pragma unroll
        for (int ni = 0; ni < 4; ++ni) {
          int l = wl * 64 + ni * 16 + c;
          f16x4 ev = *(const f16x4*)&E[l * 128 + ((yg ^ c) << 2)];
          #pragma unroll
          for (int v = 0; v < 4; ++v)
            redP[mi][v] += (float)ev[v] * acc[mi][ni][v];
        }
      }
    }
  }

  // reduce across the 16 lanes sharing each y row, then global atomics
  for (int m = 1; m < 16; m <<= 1)
    #pragma unroll
    for (int mi = 0; mi < 4; ++mi)
      for (int v = 0; v < 4; ++v)
        redP[mi][v] += __shfl_xor(redP[mi][v], m, 64);
  if ((lane & 15) == 0) {
    float* dst = accG + (g ? B_ * YP : 0);
    #pragma unroll
    for (int mi = 0; mi < 4; ++mi)
      for (int v = 0; v < 4; ++v) {
        int y = yt * 128 + wy * 64 + mi * 16 + gb * 4 + v;
        atomicAdd(&dst[b * YP + y], redP[mi][v]);
      }
  }
}

__global__ void k_final(const float* __restrict__ accG,
                        const float* __restrict__ fb,
                        float* __restrict__ out) {
  int id = blockIdx.x * 256 + threadIdx.x;
  if (id >= B_ * Y_) return;
  int b = id / Y_, y = id - b * Y_;
  float den = accG[b * YP + y] - (float)(LP - L_);
  out[id] = accG[B_ * YP + b * YP + y] / den + fb[y];
}

__global__ void k_loss(const float* __restrict__ y,
                       const float* __restrict__ t,
                       float* __restrict__ loss) {
  float p = 0.0f;
  for (int i = blockIdx.x * 256 + threadIdx.x; i < B_ * Y_; i += gridDim.x * 256) {
    float v = y[i], tg = t[i];
    p += fmaxf(v, 0.0f) - v * tg + log1pf(__expf(-fabsf(v)));
  }
  for (int m = 32; m; m >>= 1) p += __shfl_down(p, m, 64);
  __shared__ float wsum[4];
  int lane = threadIdx.x & 63, wv = threadIdx.x >> 6;
  if (lane == 0) wsum[wv] = p;
  __syncthreads();
  if (threadIdx.x == 0) {
    float s = wsum[0] + wsum[1] + wsum[2] + wsum[3];
    atomicAdd(loss, s * (1.0f / (float)(B_ * Y_)));
  }
}

extern "C" void kernel_launch(void* const* d_in, const int* in_sizes, int n_in,
                              void* d_out, int out_size, void* d_ws, size_t ws_size,
                              hipStream_t stream) {
  (void)in_sizes; (void)n_in; (void)out_size; (void)ws_size;
  const float* x       = (const float*)d_in[0];
  const float* target  = (const float*)d_in[1];
  const float* U_w     = (const float*)d_in[3];
  const float* final_w = (const float*)d_in[4];
  const float* final_b = (const float*)d_in[5];
  float* out = (float*)d_out;
  _Float16* ws = (_Float16*)d_ws;
  float* accG = (float*)(ws + WS_F16_HALVES);

  k_convert<<<9600, 256, 0, stream>>>(x, U_w, final_w, ws, out + B_ * Y_);

  dim3 g(YP / 128, B_, 2);
  k_attn<<<g, 512, 0, stream>>>(ws, accG);

  k_final<<<(B_ * Y_ + 255) / 256, 256, 0, stream>>>(accG, final_b, out);
  k_loss<<<140, 256, 0, stream>>>(out, target, out + B_ * Y_);
}

// Round 7
// 560.478 us; speedup vs baseline: 1.1770x; 1.1770x over previous
//
#include <hip/hip_runtime.h>
#include <math.h>

#define B_  8
#define L_  2500
#define D_  512
#define Y_  8921
#define LP  2560    // L padded
#define YP  8960    // Y padded to 140*64

// ws layout: fp16 X[B_][LP][D_] | G[2*YP][D_] (U/F rows interleaved in
// 16-row groups: rows 0-7 = U[y0..y0+7], rows 8-15 = F[y0..y0+7])
// then fp32  denG[B_][YP] | numG[B_][YP]
#define WS_F16_HALVES  (B_ * LP * D_ + 2 * YP * D_)
#define ACC_FLOATS     (2 * B_ * YP)

typedef _Float16 f16x8 __attribute__((ext_vector_type(8)));
typedef float    f32x4 __attribute__((ext_vector_type(4)));

__device__ __forceinline__ void load_lds16(const _Float16* g, _Float16* l) {
  __builtin_amdgcn_global_load_lds(
      (const __attribute__((address_space(1))) unsigned int*)g,
      (__attribute__((address_space(3))) unsigned int*)l, 16, 0, 0);
}

__global__ void k_convert(const float* __restrict__ x,
                          const float* __restrict__ Uw,
                          const float* __restrict__ Fw,
                          _Float16* __restrict__ ws,
                          float* __restrict__ loss_slot) {
  if (blockIdx.x == 0 && threadIdx.x == 0) *loss_slot = 0.0f;
  const int NX = B_ * LP * (D_ / 8);   // 1310720 slots
  int idx = blockIdx.x * 256 + threadIdx.x;
  if (idx < ACC_FLOATS) ((float*)(ws + WS_F16_HALVES))[idx] = 0.0f;
  const float* src = nullptr;
  if (idx < NX) {
    int b  = idx / (LP * 64);
    int r  = idx - b * (LP * 64);
    int l  = r >> 6;
    int d8 = r & 63;
    if (l < L_) src = x + (((long)b * L_ + l) * D_ + d8 * 8);
  } else {
    int u = idx - NX;          // G slot
    int r = u >> 6;            // G row 0..17919
    int d8 = u & 63;
    int group = r >> 4, sub = r & 15;
    int y = group * 8 + (sub & 7);
    if (y < Y_) src = (sub < 8 ? Uw : Fw) + (long)y * D_ + d8 * 8;
  }
  f16x8 o;
  if (src) {
    const float4* s4 = (const float4*)src;
    float4 a = s4[0], c = s4[1];
    o[0] = (_Float16)a.x; o[1] = (_Float16)a.y; o[2] = (_Float16)a.z; o[3] = (_Float16)a.w;
    o[4] = (_Float16)c.x; o[5] = (_Float16)c.y; o[6] = (_Float16)c.z; o[7] = (_Float16)c.w;
  } else {
    for (int i = 0; i < 8; ++i) o[i] = (_Float16)0.0f;
  }
  ((f16x8*)ws)[idx] = o;
}

// Interleaved-G fused attention: one GEMM G@X^T where G rows pair U (S) and
// F (C) for the same labels inside each 16-row group. In each 16x16 C/D tile,
// S occupies rows 0-7 (lanes 0-31) and C rows 8-15 (lanes 32-63); e=exp(S)
// crosses to the C half via shfl_xor(·,32) — no LDS exchange. Wave tile
// 64G x 128l (acc 4x8), block 4 waves = 128G(64y) x 256l, BK=64, XOR-swizzled
// LDS staged via global_load_lds. Pad x rows are exactly zero -> pad cols add
// exactly (1,0) to (den,num); k_final subtracts LP-L_.
__global__ __launch_bounds__(256, 2)
void k_attn(const _Float16* __restrict__ ws,
            float* __restrict__ accG) {
  __shared__ __align__(16) _Float16 TILE[24576];   // G 16KB | X 32KB
  _Float16* GT = TILE;            // 128 rows x 64
  _Float16* XT = TILE + 8192;     // 256 rows x 64

  const int tid  = threadIdx.x;
  const int lane = tid & 63;
  const int wave = tid >> 6;           // 0..3
  const int wy = wave & 1;             // G-half (64 G rows = 32 y)
  const int wl = wave >> 1;            // l-half (128 cols)
  const int yt = blockIdx.x;           // 0..139 (64 labels each)
  const int b  = blockIdx.y;
  const int lh = blockIdx.z;

  const _Float16* Xg = ws + (long)b * LP * D_ + (long)lh * (LP / 2) * D_;
  const _Float16* Gg = ws + (long)B_ * LP * D_ + (long)yt * 128 * D_;

  // staging: 48 segments of 1KB (8 rows x 64 halves); 12 per wave
  const int srow = lane >> 3;
  const int sg8  = ((lane & 7) ^ srow) * 8;
  const _Float16* gsrc[12];
  _Float16*       gdst[12];
  #pragma unroll
  for (int i = 0; i < 12; ++i) {
    int seg = wave * 12 + i;
    const _Float16* base;
    int r;
    if (seg < 16) { base = Gg; r = seg * 8; }
    else          { base = Xg; r = (seg - 16) * 8; }   // + lt*256 rows later
    gsrc[i] = base + (long)(r + srow) * D_ + sg8;
    gdst[i] = TILE + seg * 512;
  }

  // compute geometry
  const int arow = wy * 64 + (lane & 15);
  const int xrow = wl * 128 + (lane & 15);
  const int r7   = lane & 7;
  const int gb   = lane >> 4;
  const bool sLow = (lane < 32);

  float redP[4][4];   // den partials (lanes 0-31) / num partials (lanes 32-63)
  #pragma unroll
  for (int i = 0; i < 4; ++i)
    for (int v = 0; v < 4; ++v) redP[i][v] = 0.0f;

  for (int lt = 0; lt < 5; ++lt) {
    f32x4 acc[4][8];
    #pragma unroll
    for (int mi = 0; mi < 4; ++mi)
      for (int ni = 0; ni < 8; ++ni) {
        f32x4 z = {0.0f, 0.0f, 0.0f, 0.0f};
        acc[mi][ni] = z;
      }
    const long xofs = (long)lt * 256 * D_;
    for (int kk = 0; kk < D_; kk += 64) {
      __syncthreads();
      #pragma unroll
      for (int i = 0; i < 12; ++i) {
        const _Float16* s = gsrc[i] + kk;
        if (wave * 12 + i >= 16) s += xofs;
        load_lds16(s, gdst[i]);
      }
      __syncthreads();
      #pragma unroll
      for (int ks = 0; ks < 2; ++ks) {
        int off = (((ks * 4 + gb) ^ r7) * 8);
        f16x8 bx[8];
        #pragma unroll
        for (int ni = 0; ni < 8; ++ni)
          bx[ni] = *(const f16x8*)&XT[(xrow + ni * 16) * 64 + off];
        #pragma unroll
        for (int mi = 0; mi < 4; ++mi) {
          f16x8 a = *(const f16x8*)&GT[(arow + mi * 16) * 64 + off];
          #pragma unroll
          for (int ni = 0; ni < 8; ++ni)
            acc[mi][ni] = __builtin_amdgcn_mfma_f32_16x16x32_f16(a, bx[ni], acc[mi][ni], 0, 0, 0);
        }
      }
    }
    // epilogue: low lanes hold S -> e=exp(S), den += e; shfl_xor(e,32) hands e
    // to the C half; upper lanes num += e * C. Pad cols: e=1 exact, C=0.
    #pragma unroll
    for (int mi = 0; mi < 4; ++mi)
      for (int ni = 0; ni < 8; ++ni)
        #pragma unroll
        for (int v = 0; v < 4; ++v) {
          float a = acc[mi][ni][v];
          float e = __expf(a);
          float p = __shfl_xor(e, 32, 64);
          redP[mi][v] += sLow ? e : p * a;
        }
  }

  // reduce over the 16 columns sharing each label row
  for (int m = 1; m < 16; m <<= 1)
    #pragma unroll
    for (int mi = 0; mi < 4; ++mi)
      for (int v = 0; v < 4; ++v)
        redP[mi][v] += __shfl_xor(redP[mi][v], m, 64);
  if ((lane & 15) == 0) {
    float* dst = accG + (sLow ? 0 : B_ * YP);   // den | num
    #pragma unroll
    for (int mi = 0; mi < 4; ++mi)
      for (int v = 0; v < 4; ++v) {
        int y = yt * 64 + wy * 32 + mi * 8 + ((lane >> 4) & 1) * 4 + v;
        atomicAdd(&dst[b * YP + y], redP[mi][v]);
      }
  }
}

__global__ void k_final(const float* __restrict__ accG,
                        const float* __restrict__ fb,
                        float* __restrict__ out) {
  int id = blockIdx.x * 256 + threadIdx.x;
  if (id >= B_ * Y_) return;
  int b = id / Y_, y = id - b * Y_;
  float den = accG[b * YP + y] - (float)(LP - L_);
  out[id] = accG[B_ * YP + b * YP + y] / den + fb[y];
}

__global__ void k_loss(const float* __restrict__ y,
                       const float* __restrict__ t,
                       float* __restrict__ loss) {
  float p = 0.0f;
  for (int i = blockIdx.x * 256 + threadIdx.x; i < B_ * Y_; i += gridDim.x * 256) {
    float v = y[i], tg = t[i];
    p += fmaxf(v, 0.0f) - v * tg + log1pf(__expf(-fabsf(v)));
  }
  for (int m = 32; m; m >>= 1) p += __shfl_down(p, m, 64);
  __shared__ float wsum[4];
  int lane = threadIdx.x & 63, wv = threadIdx.x >> 6;
  if (lane == 0) wsum[wv] = p;
  __syncthreads();
  if (threadIdx.x == 0) {
    float s = wsum[0] + wsum[1] + wsum[2] + wsum[3];
    atomicAdd(loss, s * (1.0f / (float)(B_ * Y_)));
  }
}

extern "C" void kernel_launch(void* const* d_in, const int* in_sizes, int n_in,
                              void* d_out, int out_size, void* d_ws, size_t ws_size,
                              hipStream_t stream) {
  (void)in_sizes; (void)n_in; (void)out_size; (void)ws_size;
  const float* x       = (const float*)d_in[0];
  const float* target  = (const float*)d_in[1];
  const float* U_w     = (const float*)d_in[3];
  const float* final_w = (const float*)d_in[4];
  const float* final_b = (const float*)d_in[5];
  float* out = (float*)d_out;
  _Float16* ws = (_Float16*)d_ws;
  float* accG = (float*)(ws + WS_F16_HALVES);

  k_convert<<<9600, 256, 0, stream>>>(x, U_w, final_w, ws, out + B_ * Y_);

  dim3 g(YP / 64, B_, 2);
  k_attn<<<g, 256, 0, stream>>>(ws, accG);

  k_final<<<(B_ * Y_ + 255) / 256, 256, 0, stream>>>(accG, final_b, out);
  k_loss<<<140, 256, 0, stream>>>(out, target, out + B_ * Y_);
}

// Round 8
// 516.127 us; speedup vs baseline: 1.2781x; 1.0859x over previous
//
#include <hip/hip_runtime.h>
#include <math.h>

#define B_  8
#define L_  2500
#define D_  512
#define Y_  8921
#define LP  2560    // L padded
#define YP  8960    // Y padded to 140*64

// ws layout: fp16 X[B_][LP][D_]
//          | G fragment-major: [yt(140)][kk2(16)][mi(8)][lane(64)][8]
//            (G row pairs U (sub 0-7) / F (sub 8-15) per 16-row group)
// then fp32  denG[B_][YP] | numG[B_][YP]
#define WS_F16_HALVES  (B_ * LP * D_ + 2 * YP * D_)
#define ACC_FLOATS     (2 * B_ * YP)

typedef _Float16 f16x8 __attribute__((ext_vector_type(8)));
typedef float    f32x4 __attribute__((ext_vector_type(4)));

__device__ __forceinline__ void load_lds16(const _Float16* g, _Float16* l) {
  __builtin_amdgcn_global_load_lds(
      (const __attribute__((address_space(1))) unsigned int*)g,
      (__attribute__((address_space(3))) unsigned int*)l, 16, 0, 0);
}

__global__ void k_convert(const float* __restrict__ x,
                          const float* __restrict__ Uw,
                          const float* __restrict__ Fw,
                          _Float16* __restrict__ ws,
                          float* __restrict__ loss_slot) {
  if (blockIdx.x == 0 && threadIdx.x == 0) *loss_slot = 0.0f;
  const int NX = B_ * LP * (D_ / 8);   // 1310720 slots
  int idx = blockIdx.x * 256 + threadIdx.x;
  if (idx < ACC_FLOATS) ((float*)(ws + WS_F16_HALVES))[idx] = 0.0f;
  const float* src = nullptr;
  if (idx < NX) {
    int b  = idx / (LP * 64);
    int r  = idx - b * (LP * 64);
    int l  = r >> 6;
    int d8 = r & 63;
    if (l < L_) src = x + (((long)b * L_ + l) * D_ + d8 * 8);
  } else {
    // G fragment-major slot: [yt][kk2][mi][lane]
    int u    = idx - NX;
    int lane = u & 63;
    int mi   = (u >> 6) & 7;
    int kk2  = (u >> 9) & 15;
    int yt   = u >> 13;
    int grow = yt * 128 + mi * 16 + (lane & 15);   // global G row
    int sub  = grow & 15;
    int y    = (grow >> 4) * 8 + (sub & 7);
    int k8   = kk2 * 4 + (lane >> 4);              // 8-elem k granule
    if (y < Y_) src = (sub < 8 ? Uw : Fw) + (long)y * D_ + k8 * 8;
  }
  f16x8 o;
  if (src) {
    const float4* s4 = (const float4*)src;
    float4 a = s4[0], c = s4[1];
    o[0] = (_Float16)a.x; o[1] = (_Float16)a.y; o[2] = (_Float16)a.z; o[3] = (_Float16)a.w;
    o[4] = (_Float16)c.x; o[5] = (_Float16)c.y; o[6] = (_Float16)c.z; o[7] = (_Float16)c.w;
  } else {
    for (int i = 0; i < 8; ++i) o[i] = (_Float16)0.0f;
  }
  ((f16x8*)ws)[idx] = o;
}

// Interleaved-G fused attention, A-operand direct from global:
// G (U/F row-paired) is pre-packed fragment-major so each wave's A-fragment
// is one coalesced 1KB global_load_dwordx4 (no LDS round trip). Only X goes
// through LDS (32KB, XOR-swizzled, global_load_lds). Wave tile 64G x 128l
// (acc 4x8), block 4 waves = 128G(64y) x 256l, BK=64.
// In each 16x16 C/D tile S sits in lanes 0-31, C in lanes 32-63 (same y);
// e=exp(S) crosses via shfl_xor(e,32). Pad x rows are exactly zero -> pad
// cols add exactly (1,0) to (den,num); k_final subtracts LP-L_.
__global__ __launch_bounds__(256, 2)
void k_attn(const _Float16* __restrict__ ws,
            float* __restrict__ accG) {
  __shared__ __align__(16) _Float16 XT[16384];   // 256 rows x 64 halves

  const int tid  = threadIdx.x;
  const int lane = tid & 63;
  const int wave = tid >> 6;           // 0..3
  const int wy = wave & 1;             // G-half (64 G rows = 32 y)
  const int wl = wave >> 1;            // l-half (128 cols)
  const int yt = blockIdx.x;           // 0..139 (64 labels each)
  const int b  = blockIdx.y;
  const int lh = blockIdx.z;

  const _Float16* Xg = ws + (long)b * LP * D_ + (long)lh * (LP / 2) * D_;
  // fragment-major G base for this yt block + this wave's row-half + lane
  const _Float16* Ga = ws + (long)B_ * LP * D_ + (long)yt * (128 * 512)
                          + (wy * 4) * 512 + lane * 8;

  // X staging: 32 segments of 1KB (8 rows x 64 halves); 8 per wave
  const int srow = lane >> 3;
  const int sg8  = ((lane & 7) ^ srow) * 8;
  const _Float16* xsrc[8];
  _Float16*       xdst[8];
  #pragma unroll
  for (int i = 0; i < 8; ++i) {
    int seg = wave * 8 + i;
    xsrc[i] = Xg + (long)(seg * 8 + srow) * D_ + sg8;   // + lt*256 rows later
    xdst[i] = XT + seg * 512;
  }

  // compute geometry
  const int xrow = wl * 128 + (lane & 15);
  const int r7   = lane & 7;
  const int gb   = lane >> 4;
  const bool sLow = (lane < 32);

  float redP[4][4];   // den partials (lanes 0-31) / num partials (lanes 32-63)
  #pragma unroll
  for (int i = 0; i < 4; ++i)
    for (int v = 0; v < 4; ++v) redP[i][v] = 0.0f;

  for (int lt = 0; lt < 5; ++lt) {
    f32x4 acc[4][8];
    #pragma unroll
    for (int mi = 0; mi < 4; ++mi)
      for (int ni = 0; ni < 8; ++ni) {
        f32x4 z = {0.0f, 0.0f, 0.0f, 0.0f};
        acc[mi][ni] = z;
      }
    const long xofs = (long)lt * 256 * D_;
    for (int kkstep = 0; kkstep < 8; ++kkstep) {
      // A-fragments direct from global (L2) — issued before the barriers so
      // their latency hides under the X stage + drain window
      f16x8 au[2][4];
      #pragma unroll
      for (int ks = 0; ks < 2; ++ks)
        #pragma unroll
        for (int mi = 0; mi < 4; ++mi)
          au[ks][mi] = *(const f16x8*)(Ga + (size_t)(kkstep * 2 + ks) * 4096 + mi * 512);
      __syncthreads();
      #pragma unroll
      for (int i = 0; i < 8; ++i)
        load_lds16(xsrc[i] + xofs + kkstep * 64, xdst[i]);
      __syncthreads();
      #pragma unroll
      for (int ks = 0; ks < 2; ++ks) {
        int off = (((ks * 4 + gb) ^ r7) * 8);
        f16x8 bx[8];
        #pragma unroll
        for (int ni = 0; ni < 8; ++ni)
          bx[ni] = *(const f16x8*)&XT[(xrow + ni * 16) * 64 + off];
        #pragma unroll
        for (int mi = 0; mi < 4; ++mi)
          #pragma unroll
          for (int ni = 0; ni < 8; ++ni)
            acc[mi][ni] = __builtin_amdgcn_mfma_f32_16x16x32_f16(au[ks][mi], bx[ni], acc[mi][ni], 0, 0, 0);
      }
    }
    // epilogue: low lanes hold S -> e=exp(S), den += e; shfl_xor(e,32) hands e
    // to the C half; upper lanes num += e * C. Pad cols: e=1 exact, C=0.
    #pragma unroll
    for (int mi = 0; mi < 4; ++mi)
      for (int ni = 0; ni < 8; ++ni)
        #pragma unroll
        for (int v = 0; v < 4; ++v) {
          float a = acc[mi][ni][v];
          float e = __expf(a);
          float p = __shfl_xor(e, 32, 64);
          redP[mi][v] += sLow ? e : p * a;
        }
  }

  // reduce over the 16 columns sharing each label row
  for (int m = 1; m < 16; m <<= 1)
    #pragma unroll
    for (int mi = 0; mi < 4; ++mi)
      for (int v = 0; v < 4; ++v)
        redP[mi][v] += __shfl_xor(redP[mi][v], m, 64);
  if ((lane & 15) == 0) {
    float* dst = accG + (sLow ? 0 : B_ * YP);   // den | num
    #pragma unroll
    for (int mi = 0; mi < 4; ++mi)
      for (int v = 0; v < 4; ++v) {
        int y = yt * 64 + wy * 32 + mi * 8 + ((lane >> 4) & 1) * 4 + v;
        atomicAdd(&dst[b * YP + y], redP[mi][v]);
      }
  }
}

__global__ void k_final(const float* __restrict__ accG,
                        const float* __restrict__ fb,
                        float* __restrict__ out) {
  int id = blockIdx.x * 256 + threadIdx.x;
  if (id >= B_ * Y_) return;
  int b = id / Y_, y = id - b * Y_;
  float den = accG[b * YP + y] - (float)(LP - L_);
  out[id] = accG[B_ * YP + b * YP + y] / den + fb[y];
}

__global__ void k_loss(const float* __restrict__ y,
                       const float* __restrict__ t,
                       float* __restrict__ loss) {
  float p = 0.0f;
  for (int i = blockIdx.x * 256 + threadIdx.x; i < B_ * Y_; i += gridDim.x * 256) {
    float v = y[i], tg = t[i];
    p += fmaxf(v, 0.0f) - v * tg + log1pf(__expf(-fabsf(v)));
  }
  for (int m = 32; m; m >>= 1) p += __shfl_down(p, m, 64);
  __shared__ float wsum[4];
  int lane = threadIdx.x & 63, wv = threadIdx.x >> 6;
  if (lane == 0) wsum[wv] = p;
  __syncthreads();
  if (threadIdx.x == 0) {
    float s = wsum[0] + wsum[1] + wsum[2] + wsum[3];
    atomicAdd(loss, s * (1.0f / (float)(B_ * Y_)));
  }
}

extern "C" void kernel_launch(void* const* d_in, const int* in_sizes, int n_in,
                              void* d_out, int out_size, void* d_ws, size_t ws_size,
                              hipStream_t stream) {
  (void)in_sizes; (void)n_in; (void)out_size; (void)ws_size;
  const float* x       = (const float*)d_in[0];
  const float* target  = (const float*)d_in[1];
  const float* U_w     = (const float*)d_in[3];
  const float* final_w = (const float*)d_in[4];
  const float* final_b = (const float*)d_in[5];
  float* out = (float*)d_out;
  _Float16* ws = (_Float16*)d_ws;
  float* accG = (float*)(ws + WS_F16_HALVES);

  k_convert<<<9600, 256, 0, stream>>>(x, U_w, final_w, ws, out + B_ * Y_);

  dim3 g(YP / 64, B_, 2);
  k_attn<<<g, 256, 0, stream>>>(ws, accG);

  k_final<<<(B_ * Y_ + 255) / 256, 256, 0, stream>>>(accG, final_b, out);
  k_loss<<<140, 256, 0, stream>>>(out, target, out + B_ * Y_);
}